// Round 6
// baseline (32098.444 us; speedup 1.0000x reference)
//
#include <hip/hip_runtime.h>

#define BB    128
#define SEQL  336
#define PREDN 24
#define IN    64
#define HH    256
#define GG    1024          // 4*H
#define KTOT  320           // IN + H
#define NBLK  256

// ---- static device scratch (~7 MB .bss; re-initialized by prep every call) ----
__device__ float g_wt_enc[2 * KTOT * GG];    // [dir][k][n][gate] float4-interleaved
__device__ float g_wt_dec[2 * KTOT * GG];
__device__ float g_linwt[2 * HH * IN];       // [k2][o]
__device__ float g_bs_enc[2 * GG];
__device__ float g_bs_dec[2 * GG];
__device__ float g_linb[IN];
__device__ float g_h[2][2 * BB * HH];        // ping-pong [p][dir][b][n]
__device__ float g_ys[PREDN * BB * IN];      // fp32 decoder feedback
__device__ int   g_flag[NBLK * 16];          // per-block event counter, 64 B apart

#define N_WT   (2 * KTOT * GG)               // 655360
#define N_PREP (2 * N_WT + 2 * HH * IN + 4 * GG + IN + 2 * 2 * BB * HH + PREDN * BB * IN + NBLK * 16)

// Transpose weights into [dir][k][n][gate] (float4 per n), combine biases,
// zero h/ys/flags. ALL INPUTS ARE FLOAT32.
__global__ void prep_kernel(const float* __restrict__ eWih,
                            const float* __restrict__ eWhh,
                            const float* __restrict__ ebih,
                            const float* __restrict__ ebhh,
                            const float* __restrict__ dWih,
                            const float* __restrict__ dWhh,
                            const float* __restrict__ dbih,
                            const float* __restrict__ dbhh,
                            const float* __restrict__ linW,
                            const float* __restrict__ linb)
{
    int idx = blockIdx.x * 256 + threadIdx.x;
    if (idx >= N_PREP) return;

    if (idx < N_WT) {                 // enc
        int d  = idx / (KTOT * GG);
        int r2 = idx % (KTOT * GG);
        int k  = r2 / GG;
        int q  = r2 % GG;
        int nn = q >> 2, g = q & 3;
        int j  = g * HH + nn;
        g_wt_enc[idx] = (k < IN) ? eWih[(d * GG + j) * IN + k]
                                 : eWhh[(d * GG + j) * HH + (k - IN)];
        return;
    }
    idx -= N_WT;
    if (idx < N_WT) {                 // dec
        int d  = idx / (KTOT * GG);
        int r2 = idx % (KTOT * GG);
        int k  = r2 / GG;
        int q  = r2 % GG;
        int nn = q >> 2, g = q & 3;
        int j  = g * HH + nn;
        g_wt_dec[idx] = (k < IN) ? dWih[(d * GG + j) * IN + k]
                                 : dWhh[(d * GG + j) * HH + (k - IN)];
        return;
    }
    idx -= N_WT;
    if (idx < 2 * HH * IN) {          // linWT[k2][o]
        int k = idx / IN, o = idx % IN;
        g_linwt[idx] = linW[o * (2 * HH) + k];
        return;
    }
    idx -= 2 * HH * IN;
    if (idx < 2 * GG) { g_bs_enc[idx] = ebih[idx] + ebhh[idx]; return; }
    idx -= 2 * GG;
    if (idx < 2 * GG) { g_bs_dec[idx] = dbih[idx] + dbhh[idx]; return; }
    idx -= 2 * GG;
    if (idx < IN) { g_linb[idx] = linb[idx]; return; }
    idx -= IN;
    if (idx < 2 * 2 * BB * HH) { ((float*)g_h)[idx] = 0.0f; return; }
    idx -= 2 * 2 * BB * HH;
    if (idx < PREDN * BB * IN) { g_ys[idx] = 0.0f; return; }
    idx -= PREDN * BB * IN;
    if (idx < NBLK * 16) { g_flag[idx] = 0; return; }
}

__device__ __forceinline__ float sigm(float v) { return 1.0f / (1.0f + expf(-v)); }

// Persistent cooperative kernel. 256 blocks x 256 threads.
// blk = dir*128 + btile*16 + ntile. Thread: nl=tid&15 (n), bl=tid>>4 (b).
// Weights for the block's 16-n slice live in LDS for a whole phase.
// Recurrence closes within the 16-block (dir,btile) group -> flag sync only
// among 16 blocks (32 at head events). c stays in a register throughout.
__global__ __launch_bounds__(256)
void lstm_main(const float* __restrict__ x, float* __restrict__ out)
{
    __shared__ float4 w4[KTOT * 16];       // 81920 B  [k][n_local]
    __shared__ float  um[16 * 516];        // 33024 B  acts rows / head h-stage (stride 516)
    __shared__ float  part[16 * 16 * 2];   //  2048 B  head partials

    const int tid   = threadIdx.x;
    const int blk   = blockIdx.x;
    const int dir   = blk >> 7;
    const int btile = (blk >> 4) & 7;
    const int ntile = blk & 15;
    const int nl    = tid & 15;
    const int bl    = tid >> 4;
    const int n0    = ntile * 16;
    const int b0    = btile * 16;
    const int n     = n0 + nl;
    const int b     = b0 + bl;

    int* myflag = &g_flag[blk * 16];
    int  ev = 0;

    // group sync: release own event, wait for nwait group members (16 same-dir / 32 both-dir)
    auto sync_g = [&](int nwait) {
        ++ev;
        __threadfence();                       // drain + make h/y stores visible (agent)
        __syncthreads();                       // all waves fenced
        if (tid == 0)
            __hip_atomic_store(myflag, ev, __ATOMIC_RELEASE, __HIP_MEMORY_SCOPE_AGENT);
        if (tid < nwait) {
            int d = (nwait == 32) ? (tid >> 4) : dir;
            int m = tid & 15;
            int* f = &g_flag[(((d << 3) | btile) * 16 + m) * 16];
            while (__hip_atomic_load(f, __ATOMIC_ACQUIRE, __HIP_MEMORY_SCOPE_AGENT) < ev)
                __builtin_amdgcn_s_sleep(2);
        }
        __syncthreads();
        __threadfence();                       // L1 invalidate on every wave before re-reading g_h/g_ys
    };

    float4 bias;
    auto load_w = [&](const float* wsrc, const float* bsrc) {
        const float4* w4g = (const float4*)wsrc + dir * (KTOT * 256);
        for (int i = tid; i < KTOT * 16; i += 256) {
            int k = i >> 4, nn = i & 15;       // i == k*16+nn
            w4[i] = w4g[k * 256 + n0 + nn];
        }
        const float* bs = bsrc + dir * GG;
        bias = make_float4(bs[n], bs[256 + n], bs[512 + n], bs[768 + n]);
        __syncthreads();
    };

    float c = 0.0f;
    int   p = 0;

    // mode 0: encoder step tval (dir-reflected); 1: decoder t=0 (x last step);
    // 2: decoder feedback sub-step tval of length L (dir-reflected).
    auto step = [&](int mode, int tval, int L) {
        const float* hsrc = g_h[p];
        // stage x/y part: 16 b x 16 float4
        {
            int bl2 = tid >> 4, j = tid & 15;
            const float* src;
            if (mode == 0)      { int te = dir ? (SEQL - 1 - tval) : tval; src = x + ((b0 + bl2) * SEQL + te) * IN; }
            else if (mode == 1) { src = x + ((b0 + bl2) * SEQL + (SEQL - 1)) * IN; }
            else                { int e = dir ? (L - 1 - tval) : tval;     src = g_ys + (e * BB + b0 + bl2) * IN; }
            float4 v = ((const float4*)src)[j];
            *(float4*)&um[bl2 * 516 + 4 * j] = v;
        }
        // stage h part: 16 b x 64 float4 (4 per thread), coalesced
        for (int i = tid; i < 16 * 64; i += 256) {
            int bl2 = i >> 6, j = i & 63;
            float4 v = ((const float4*)(hsrc + (dir * BB + b0 + bl2) * HH))[j];
            *(float4*)&um[bl2 * 516 + IN + 4 * j] = v;
        }
        __syncthreads();

        float a0 = bias.x, a1 = bias.y, a2 = bias.z, a3 = bias.w;
        const float* arow = &um[bl * 516];
        #pragma unroll 4
        for (int k4 = 0; k4 < KTOT / 4; ++k4) {
            float4 av = *(const float4*)&arow[4 * k4];
            float4 w0 = w4[(4 * k4 + 0) * 16 + nl];
            float4 w1 = w4[(4 * k4 + 1) * 16 + nl];
            float4 w2 = w4[(4 * k4 + 2) * 16 + nl];
            float4 w3 = w4[(4 * k4 + 3) * 16 + nl];
            a0 = fmaf(av.x, w0.x, a0); a1 = fmaf(av.x, w0.y, a1); a2 = fmaf(av.x, w0.z, a2); a3 = fmaf(av.x, w0.w, a3);
            a0 = fmaf(av.y, w1.x, a0); a1 = fmaf(av.y, w1.y, a1); a2 = fmaf(av.y, w1.z, a2); a3 = fmaf(av.y, w1.w, a3);
            a0 = fmaf(av.z, w2.x, a0); a1 = fmaf(av.z, w2.y, a1); a2 = fmaf(av.z, w2.z, a2); a3 = fmaf(av.z, w2.w, a3);
            a0 = fmaf(av.w, w3.x, a0); a1 = fmaf(av.w, w3.y, a1); a2 = fmaf(av.w, w3.z, a2); a3 = fmaf(av.w, w3.w, a3);
        }
        float ig = sigm(a0);
        float fg = sigm(a1);
        float gt = tanhf(a2);
        float og = sigm(a3);
        c = fg * c + ig * gt;
        g_h[p ^ 1][(dir * BB + b) * HH + n] = og * tanhf(c);
        p ^= 1;
    };

    // ---------------- encoder: 336 steps ----------------
    load_w(g_wt_enc, g_bs_enc);
    for (int t = 0; t < SEQL; ++t) { step(0, t, 0); sync_g(16); }

    // switch to decoder weights (LDS-local; prior sync's barrier covers reuse)
    load_w(g_wt_dec, g_bs_dec);

    // ---------------- decoder: 24 iterations ----------------
    for (int t = 0; t < PREDN; ++t) {
        int L = t ? t : 1;
        for (int s = 0; s < L; ++s) {
            step((t == 0) ? 1 : 2, s, L);
            sync_g((s == L - 1) ? 32 : 16);    // final sub-step: align both dirs for head
        }
        // ---- linear head: y = concat(hF,hB) @ linW^T + b; block computes its 16 b x 2 o ----
        {
            const float* hc = g_h[p];
            for (int i = tid; i < 16 * 128; i += 256) {     // stage 16 b x 512 k into um
                int bl2 = i >> 7, j = i & 127;
                float4 v = (j < 64) ? ((const float4*)(hc + (b0 + bl2) * HH))[j]
                                    : ((const float4*)(hc + (BB + b0 + bl2) * HH))[j - 64];
                *(float4*)&um[bl2 * 516 + 4 * j] = v;
            }
            __syncthreads();
            int bl2 = tid >> 4, ks = tid & 15;
            int o0  = ((dir << 4) | ntile) << 1;            // 2 outputs per block
            float p0 = 0.0f, p1 = 0.0f;
            const float* hr = &um[bl2 * 516 + ks * 32];
            const float* lw = g_linwt + (ks * 32) * IN + o0;
            #pragma unroll 8
            for (int j = 0; j < 32; ++j) {
                float hv = hr[j];
                p0 = fmaf(hv, lw[j * IN],     p0);
                p1 = fmaf(hv, lw[j * IN + 1], p1);
            }
            part[(bl2 * 16 + ks) * 2]     = p0;
            part[(bl2 * 16 + ks) * 2 + 1] = p1;
            __syncthreads();
            if (tid < 32) {
                int b2 = tid >> 1, oi = tid & 1;
                float acc = g_linb[o0 + oi];
                #pragma unroll
                for (int m2 = 0; m2 < 16; ++m2) acc += part[(b2 * 16 + m2) * 2 + oi];
                g_ys[(t * BB + b0 + b2) * IN + o0 + oi] = acc;            // fp32 feedback
                out[(b0 + b2) * (PREDN * IN) + t * IN + o0 + oi] = acc;   // fp32 output
            }
            sync_g(32);
        }
    }
}

extern "C" void kernel_launch(void* const* d_in, const int* in_sizes, int n_in,
                              void* d_out, int out_size, void* d_ws, size_t ws_size,
                              hipStream_t stream)
{
    (void)in_sizes; (void)n_in; (void)out_size; (void)d_ws; (void)ws_size;
    const float* x    = (const float*)d_in[0];
    const float* eWih = (const float*)d_in[1];
    const float* eWhh = (const float*)d_in[2];
    const float* ebih = (const float*)d_in[3];
    const float* ebhh = (const float*)d_in[4];
    const float* dWih = (const float*)d_in[5];
    const float* dWhh = (const float*)d_in[6];
    const float* dbih = (const float*)d_in[7];
    const float* dbhh = (const float*)d_in[8];
    const float* linW = (const float*)d_in[9];
    const float* linb = (const float*)d_in[10];
    float* out = (float*)d_out;

    int prep_blocks = (N_PREP + 255) / 256;
    hipLaunchKernelGGL(prep_kernel, dim3(prep_blocks), dim3(256), 0, stream,
                       eWih, eWhh, ebih, ebhh, dWih, dWhh, dbih, dbhh, linW, linb);

    void* args[] = { (void*)&x, (void*)&out };
    hipLaunchCooperativeKernel((void*)lstm_main, dim3(NBLK), dim3(256), args, 0, stream);
}

// Round 8
// 9409.525 us; speedup vs baseline: 3.4113x; 3.4113x over previous
//
#include <hip/hip_runtime.h>

#define BB    128
#define SEQL  336
#define PREDN 24
#define IN    64
#define HH    256
#define GG    1024          // 4*H
#define KTOT  320           // IN + H
#define NBLK  256

// ---- static device scratch (~7 MB .bss; re-initialized by prep every call) ----
__device__ float g_wt_enc[2 * KTOT * GG];    // [dir][k][n][gate] float4-interleaved
__device__ float g_wt_dec[2 * KTOT * GG];
__device__ float g_linwt[2 * HH * IN];       // [k2][o]
__device__ float g_bs_enc[2 * GG];
__device__ float g_bs_dec[2 * GG];
__device__ float g_linb[IN];
__device__ float g_h[2][2 * BB * HH];        // ping-pong [p][dir][b][n]
__device__ float g_ys[PREDN * BB * IN];      // fp32 decoder feedback
__device__ int   g_flag[NBLK * 16];          // per-block event counter, 64 B apart

#define N_WT   (2 * KTOT * GG)               // 655360
#define N_PREP (2 * N_WT + 2 * HH * IN + 4 * GG + IN + 2 * 2 * BB * HH + PREDN * BB * IN + NBLK * 16)

// Transpose weights into [dir][k][n][gate] (float4 per n), combine biases,
// zero h/ys/flags. ALL INPUTS ARE FLOAT32.
__global__ void prep_kernel(const float* __restrict__ eWih,
                            const float* __restrict__ eWhh,
                            const float* __restrict__ ebih,
                            const float* __restrict__ ebhh,
                            const float* __restrict__ dWih,
                            const float* __restrict__ dWhh,
                            const float* __restrict__ dbih,
                            const float* __restrict__ dbhh,
                            const float* __restrict__ linW,
                            const float* __restrict__ linb)
{
    int idx = blockIdx.x * 256 + threadIdx.x;
    if (idx >= N_PREP) return;

    if (idx < N_WT) {                 // enc
        int d  = idx / (KTOT * GG);
        int r2 = idx % (KTOT * GG);
        int k  = r2 / GG;
        int q  = r2 % GG;
        int nn = q >> 2, g = q & 3;
        int j  = g * HH + nn;
        g_wt_enc[idx] = (k < IN) ? eWih[(d * GG + j) * IN + k]
                                 : eWhh[(d * GG + j) * HH + (k - IN)];
        return;
    }
    idx -= N_WT;
    if (idx < N_WT) {                 // dec
        int d  = idx / (KTOT * GG);
        int r2 = idx % (KTOT * GG);
        int k  = r2 / GG;
        int q  = r2 % GG;
        int nn = q >> 2, g = q & 3;
        int j  = g * HH + nn;
        g_wt_dec[idx] = (k < IN) ? dWih[(d * GG + j) * IN + k]
                                 : dWhh[(d * GG + j) * HH + (k - IN)];
        return;
    }
    idx -= N_WT;
    if (idx < 2 * HH * IN) {          // linWT[k2][o]
        int k = idx / IN, o = idx % IN;
        g_linwt[idx] = linW[o * (2 * HH) + k];
        return;
    }
    idx -= 2 * HH * IN;
    if (idx < 2 * GG) { g_bs_enc[idx] = ebih[idx] + ebhh[idx]; return; }
    idx -= 2 * GG;
    if (idx < 2 * GG) { g_bs_dec[idx] = dbih[idx] + dbhh[idx]; return; }
    idx -= 2 * GG;
    if (idx < IN) { g_linb[idx] = linb[idx]; return; }
    idx -= IN;
    if (idx < 2 * 2 * BB * HH) { ((float*)g_h)[idx] = 0.0f; return; }
    idx -= 2 * 2 * BB * HH;
    if (idx < PREDN * BB * IN) { g_ys[idx] = 0.0f; return; }
    idx -= PREDN * BB * IN;
    if (idx < NBLK * 16) { g_flag[idx] = 0; return; }
}

__device__ __forceinline__ float sigm(float v) { return 1.0f / (1.0f + expf(-v)); }

__device__ __forceinline__ float agent_ld(const float* p) {
    return __hip_atomic_load(p, __ATOMIC_RELAXED, __HIP_MEMORY_SCOPE_AGENT);
}
__device__ __forceinline__ void agent_st(float* p, float v) {
    __hip_atomic_store(p, v, __ATOMIC_RELAXED, __HIP_MEMORY_SCOPE_AGENT);
}

// Persistent cooperative kernel. 256 blocks x 256 threads.
// blk = dir*128 + btile*16 + ntile. Thread: nl=tid&15 (n), bl=tid>>4 (b).
// Weights live in LDS for a whole phase. Recurrence closes within the
// 16-block (dir,btile) group. ALL cross-block data (g_h, g_ys) moves via
// 32-bit agent-scope relaxed atomics (coherence point = LLC; no
// __threadfence, which in round 6 caused 1.1 GB of HBM cache-maint traffic
// and 50 us/step). c stays in a register throughout.
__global__ __launch_bounds__(256)
void lstm_main(const float* __restrict__ x, float* __restrict__ out)
{
    __shared__ float4 w4[KTOT * 16];                     // 81920 B [k][n_local]
    __shared__ __align__(16) float um[16 * 516];         // 33024 B acts rows (stride 516)
    __shared__ float part[16 * 16 * 2];                  //  2048 B head partials

    const int tid   = threadIdx.x;
    const int blk   = blockIdx.x;
    const int dir   = blk >> 7;
    const int btile = (blk >> 4) & 7;
    const int ntile = blk & 15;
    const int nl    = tid & 15;
    const int bl    = tid >> 4;
    const int n0    = ntile * 16;
    const int b0    = btile * 16;
    const int n     = n0 + nl;
    const int b     = b0 + bl;

    int* myflag = &g_flag[blk * 16];
    int  ev = 0;

    // group sync: drain own stores (per wave!), release own event flag,
    // wait for nwait group members (16 same-dir / 32 both-dir).
    auto sync_g = [&](int nwait) {
        ++ev;
        __builtin_amdgcn_s_waitcnt(0);     // each wave drains its own h/ys stores
        __syncthreads();                   // all waves drained
        if (tid == 0)
            __hip_atomic_store(myflag, ev, __ATOMIC_RELEASE, __HIP_MEMORY_SCOPE_AGENT);
        if (tid < nwait) {
            int d = (nwait == 32) ? (tid >> 4) : dir;
            int m = tid & 15;
            int* f = &g_flag[(((d << 3) | btile) * 16 + m) * 16];
            while (__hip_atomic_load(f, __ATOMIC_ACQUIRE, __HIP_MEMORY_SCOPE_AGENT) < ev)
                __builtin_amdgcn_s_sleep(1);
        }
        __syncthreads();
    };

    float4 bias;
    auto load_w = [&](const float* wsrc, const float* bsrc) {
        const float4* w4g = (const float4*)wsrc + dir * (KTOT * 256);
        for (int i = tid; i < KTOT * 16; i += 256) {
            int k = i >> 4, nn = i & 15;
            w4[i] = w4g[k * 256 + n0 + nn];
        }
        const float* bs = bsrc + dir * GG;
        bias = make_float4(bs[n], bs[256 + n], bs[512 + n], bs[768 + n]);
        __syncthreads();
    };

    float c = 0.0f;
    int   p = 0;

    // mode 0: encoder step tval (dir-reflected); 1: decoder t=0 (x last step);
    // 2: decoder feedback sub-step tval of length L (dir-reflected).
    auto step = [&](int mode, int tval, int L) {
        float* hsrc = g_h[p];
        // stage x/y part: 16 b x 64 floats
        if (mode <= 1) {                   // x: read-only input, plain loads
            int bl2 = tid >> 4, j = tid & 15;
            int te = (mode == 0) ? (dir ? (SEQL - 1 - tval) : tval) : (SEQL - 1);
            float4 v = ((const float4*)(x + ((b0 + bl2) * SEQL + te) * IN))[j];
            *(float4*)&um[bl2 * 516 + 4 * j] = v;
        } else {                           // ys: cross-block data -> agent atomics
            int e = dir ? (L - 1 - tval) : tval;
            for (int i = tid; i < 16 * 64; i += 256) {
                int bl2 = i >> 6, j = i & 63;
                um[bl2 * 516 + j] = agent_ld(g_ys + (e * BB + b0 + bl2) * IN + j);
            }
        }
        // stage h part: 16 b x 256 floats, agent atomics (cross-block, cross-XCD)
        for (int i = tid; i < 16 * 256; i += 256) {
            int bl2 = i >> 8, j = i & 255;
            um[bl2 * 516 + IN + j] = agent_ld(hsrc + (dir * BB + b0 + bl2) * HH + j);
        }
        __syncthreads();

        float a0 = bias.x, a1 = bias.y, a2 = bias.z, a3 = bias.w;
        const float* arow = &um[bl * 516];
        #pragma unroll 4
        for (int k4 = 0; k4 < KTOT / 4; ++k4) {
            float4 av = *(const float4*)&arow[4 * k4];
            float4 w0 = w4[(4 * k4 + 0) * 16 + nl];
            float4 w1 = w4[(4 * k4 + 1) * 16 + nl];
            float4 w2 = w4[(4 * k4 + 2) * 16 + nl];
            float4 w3 = w4[(4 * k4 + 3) * 16 + nl];
            a0 = fmaf(av.x, w0.x, a0); a1 = fmaf(av.x, w0.y, a1); a2 = fmaf(av.x, w0.z, a2); a3 = fmaf(av.x, w0.w, a3);
            a0 = fmaf(av.y, w1.x, a0); a1 = fmaf(av.y, w1.y, a1); a2 = fmaf(av.y, w1.z, a2); a3 = fmaf(av.y, w1.w, a3);
            a0 = fmaf(av.z, w2.x, a0); a1 = fmaf(av.z, w2.y, a1); a2 = fmaf(av.z, w2.z, a2); a3 = fmaf(av.z, w2.w, a3);
            a0 = fmaf(av.w, w3.x, a0); a1 = fmaf(av.w, w3.y, a1); a2 = fmaf(av.w, w3.z, a2); a3 = fmaf(av.w, w3.w, a3);
        }
        float ig = sigm(a0);
        float fg = sigm(a1);
        float gt = tanhf(a2);
        float og = sigm(a3);
        c = fg * c + ig * gt;
        float hn = og * tanhf(c);
        agent_st(&g_h[p ^ 1][(dir * BB + b) * HH + n], hn);
        p ^= 1;
    };

    // ---------------- encoder: 336 steps ----------------
    load_w(g_wt_enc, g_bs_enc);
    for (int t = 0; t < SEQL; ++t) { step(0, t, 0); sync_g(16); }

    // switch to decoder weights (LDS reuse protected by the barrier in load_w/sync_g)
    load_w(g_wt_dec, g_bs_dec);

    // ---------------- decoder: 24 iterations ----------------
    for (int t = 0; t < PREDN; ++t) {
        int L = t ? t : 1;
        for (int s = 0; s < L; ++s) {
            step((t == 0) ? 1 : 2, s, L);
            sync_g((s == L - 1) ? 32 : 16);    // final sub-step: align both dirs for head
        }
        // ---- linear head: y = concat(hF,hB) @ linW^T + b; 16 b x 2 o per block ----
        {
            float* hc = g_h[p];
            for (int i = tid; i < 16 * 512; i += 256) {     // 16 b x 512 k via agent atomics
                int bl2 = i >> 9, j = i & 511;
                const float* base = (j < 256) ? (hc + (b0 + bl2) * HH + j)
                                              : (hc + (BB + b0 + bl2) * HH + (j - 256));
                um[bl2 * 516 + j] = agent_ld(base);
            }
            __syncthreads();
            int bl2 = tid >> 4, ks = tid & 15;
            int o0  = ((dir << 4) | ntile) << 1;            // 2 outputs per block
            float p0 = 0.0f, p1 = 0.0f;
            const float* hr = &um[bl2 * 516 + ks * 32];
            const float* lw = g_linwt + (ks * 32) * IN + o0;
            #pragma unroll 8
            for (int j = 0; j < 32; ++j) {
                float hv = hr[j];
                p0 = fmaf(hv, lw[j * IN],     p0);
                p1 = fmaf(hv, lw[j * IN + 1], p1);
            }
            part[(bl2 * 16 + ks) * 2]     = p0;
            part[(bl2 * 16 + ks) * 2 + 1] = p1;
            __syncthreads();
            if (tid < 32) {
                int b2 = tid >> 1, oi = tid & 1;
                float acc = g_linb[o0 + oi];
                #pragma unroll
                for (int m2 = 0; m2 < 16; ++m2) acc += part[(b2 * 16 + m2) * 2 + oi];
                agent_st(&g_ys[(t * BB + b0 + b2) * IN + o0 + oi], acc);  // fp32 feedback
                out[(b0 + b2) * (PREDN * IN) + t * IN + o0 + oi] = acc;   // fp32 output
            }
            sync_g(32);
        }
    }
}

extern "C" void kernel_launch(void* const* d_in, const int* in_sizes, int n_in,
                              void* d_out, int out_size, void* d_ws, size_t ws_size,
                              hipStream_t stream)
{
    (void)in_sizes; (void)n_in; (void)out_size; (void)d_ws; (void)ws_size;
    const float* x    = (const float*)d_in[0];
    const float* eWih = (const float*)d_in[1];
    const float* eWhh = (const float*)d_in[2];
    const float* ebih = (const float*)d_in[3];
    const float* ebhh = (const float*)d_in[4];
    const float* dWih = (const float*)d_in[5];
    const float* dWhh = (const float*)d_in[6];
    const float* dbih = (const float*)d_in[7];
    const float* dbhh = (const float*)d_in[8];
    const float* linW = (const float*)d_in[9];
    const float* linb = (const float*)d_in[10];
    float* out = (float*)d_out;

    int prep_blocks = (N_PREP + 255) / 256;
    hipLaunchKernelGGL(prep_kernel, dim3(prep_blocks), dim3(256), 0, stream,
                       eWih, eWhh, ebih, ebhh, dWih, dWhh, dbih, dbhh, linW, linb);

    void* args[] = { (void*)&x, (void*)&out };
    (void)hipLaunchCooperativeKernel((void*)lstm_main, dim3(NBLK), dim3(256), args, 0, stream);
}

// Round 9
// 6422.710 us; speedup vs baseline: 4.9976x; 1.4650x over previous
//
#include <hip/hip_runtime.h>

#define BB    128
#define SEQL  336
#define PREDN 24
#define IN    64
#define HH    256
#define GG    1024          // 4*H
#define KTOT  320           // IN + H
#define NBLK  256

// ---- static device scratch (~7 MB .bss; re-initialized by prep every call) ----
__device__ float g_wt_enc[2 * KTOT * GG];    // [dir][k][n][gate] float4-interleaved
__device__ float g_wt_dec[2 * KTOT * GG];
__device__ float g_linwt[2 * HH * IN];       // [k2][o]
__device__ float g_bs_enc[2 * GG];
__device__ float g_bs_dec[2 * GG];
__device__ float g_linb[IN];
__device__ float g_h[2][2 * BB * HH];        // ping-pong [p][dir][b][n]
__device__ float g_ys[PREDN * BB * IN];      // fp32 decoder feedback
__device__ int   g_flag[NBLK * 16];          // per-block event counter, 64 B apart

#define N_WT   (2 * KTOT * GG)               // 655360
#define N_PREP (2 * N_WT + 2 * HH * IN + 4 * GG + IN + 2 * 2 * BB * HH + PREDN * BB * IN + NBLK * 16)

// Transpose weights into [dir][k][n][gate] (float4 per n), combine biases,
// zero h/ys/flags. ALL INPUTS ARE FLOAT32.
__global__ void prep_kernel(const float* __restrict__ eWih,
                            const float* __restrict__ eWhh,
                            const float* __restrict__ ebih,
                            const float* __restrict__ ebhh,
                            const float* __restrict__ dWih,
                            const float* __restrict__ dWhh,
                            const float* __restrict__ dbih,
                            const float* __restrict__ dbhh,
                            const float* __restrict__ linW,
                            const float* __restrict__ linb)
{
    int idx = blockIdx.x * 256 + threadIdx.x;
    if (idx >= N_PREP) return;

    if (idx < N_WT) {                 // enc
        int d  = idx / (KTOT * GG);
        int r2 = idx % (KTOT * GG);
        int k  = r2 / GG;
        int q  = r2 % GG;
        int nn = q >> 2, g = q & 3;
        int j  = g * HH + nn;
        g_wt_enc[idx] = (k < IN) ? eWih[(d * GG + j) * IN + k]
                                 : eWhh[(d * GG + j) * HH + (k - IN)];
        return;
    }
    idx -= N_WT;
    if (idx < N_WT) {                 // dec
        int d  = idx / (KTOT * GG);
        int r2 = idx % (KTOT * GG);
        int k  = r2 / GG;
        int q  = r2 % GG;
        int nn = q >> 2, g = q & 3;
        int j  = g * HH + nn;
        g_wt_dec[idx] = (k < IN) ? dWih[(d * GG + j) * IN + k]
                                 : dWhh[(d * GG + j) * HH + (k - IN)];
        return;
    }
    idx -= N_WT;
    if (idx < 2 * HH * IN) {          // linWT[k2][o]
        int k = idx / IN, o = idx % IN;
        g_linwt[idx] = linW[o * (2 * HH) + k];
        return;
    }
    idx -= 2 * HH * IN;
    if (idx < 2 * GG) { g_bs_enc[idx] = ebih[idx] + ebhh[idx]; return; }
    idx -= 2 * GG;
    if (idx < 2 * GG) { g_bs_dec[idx] = dbih[idx] + dbhh[idx]; return; }
    idx -= 2 * GG;
    if (idx < IN) { g_linb[idx] = linb[idx]; return; }
    idx -= IN;
    if (idx < 2 * 2 * BB * HH) { ((float*)g_h)[idx] = 0.0f; return; }
    idx -= 2 * 2 * BB * HH;
    if (idx < PREDN * BB * IN) { g_ys[idx] = 0.0f; return; }
    idx -= PREDN * BB * IN;
    if (idx < NBLK * 16) { g_flag[idx] = 0; return; }
}

__device__ __forceinline__ float sigm(float v) { return 1.0f / (1.0f + expf(-v)); }

__device__ __forceinline__ float agent_ld(const float* p) {
    return __hip_atomic_load(p, __ATOMIC_RELAXED, __HIP_MEMORY_SCOPE_AGENT);
}
__device__ __forceinline__ void agent_st(float* p, float v) {
    __hip_atomic_store(p, v, __ATOMIC_RELAXED, __HIP_MEMORY_SCOPE_AGENT);
}

// Persistent cooperative kernel. 256 blocks x 256 threads.
// blk = dir*128 + btile*16 + ntile. Thread: nl=tid&15 (n), bl=tid>>4 (b).
// Weights live in LDS for a whole phase. Recurrence closes within the
// 16-block (dir,btile) group. ALL cross-block data (g_h, g_ys) moves via
// 32-bit RELAXED agent-scope atomics: these lower to sc1 loads/stores that
// bypass L1/L2 straight to the Infinity Cache coherence point, so NO
// acquire/release fences (and their L2 invalidate/writeback cache-maint ops,
// which cost 13.5 us/step in round 8) are needed anywhere. HW ordering:
// s_waitcnt(0) drains sc1 stores to IC before the flag is raised; consumer
// sc1 loads always read IC, so they cannot see stale data.
__global__ __launch_bounds__(256)
void lstm_main(const float* __restrict__ x, float* __restrict__ out)
{
    __shared__ float4 w4[KTOT * 16];                     // 81920 B [k][n_local]
    __shared__ __align__(16) float um[16 * 516];         // 33024 B acts rows (stride 516)
    __shared__ float part[16 * 16 * 2];                  //  2048 B head partials

    const int tid   = threadIdx.x;
    const int blk   = blockIdx.x;
    const int dir   = blk >> 7;
    const int btile = (blk >> 4) & 7;
    const int ntile = blk & 15;
    const int nl    = tid & 15;
    const int bl    = tid >> 4;
    const int n0    = ntile * 16;
    const int b0    = btile * 16;
    const int n     = n0 + nl;
    const int b     = b0 + bl;

    int* myflag = &g_flag[blk * 16];
    int  ev = 0;

    // group sync: drain own sc1 stores (per wave!), raise own flag (relaxed),
    // poll group members' flags (relaxed). Zero cache-maintenance ops.
    auto sync_g = [&](int nwait) {
        ++ev;
        __atomic_signal_fence(__ATOMIC_SEQ_CST);
        __builtin_amdgcn_s_waitcnt(0);     // this wave's h/ys stores reached IC
        __atomic_signal_fence(__ATOMIC_SEQ_CST);
        __syncthreads();                   // all waves drained
        if (tid == 0)
            __hip_atomic_store(myflag, ev, __ATOMIC_RELAXED, __HIP_MEMORY_SCOPE_AGENT);
        if (tid < nwait) {
            int d = (nwait == 32) ? (tid >> 4) : dir;
            int m = tid & 15;
            int* f = &g_flag[(((d << 3) | btile) * 16 + m) * 16];
            while (__hip_atomic_load(f, __ATOMIC_RELAXED, __HIP_MEMORY_SCOPE_AGENT) < ev)
                __builtin_amdgcn_s_sleep(1);
        }
        __atomic_signal_fence(__ATOMIC_SEQ_CST);
        __syncthreads();
    };

    float4 bias;
    auto load_w = [&](const float* wsrc, const float* bsrc) {
        const float4* w4g = (const float4*)wsrc + dir * (KTOT * 256);
        for (int i = tid; i < KTOT * 16; i += 256) {
            int k = i >> 4, nn = i & 15;
            w4[i] = w4g[k * 256 + n0 + nn];
        }
        const float* bs = bsrc + dir * GG;
        bias = make_float4(bs[n], bs[256 + n], bs[512 + n], bs[768 + n]);
        __syncthreads();
    };

    float c = 0.0f;
    int   p = 0;

    // mode 0: encoder step tval (dir-reflected); 1: decoder t=0 (x last step);
    // 2: decoder feedback sub-step tval of length L (dir-reflected).
    auto step = [&](int mode, int tval, int L) {
        float* hsrc = g_h[p];
        // stage x/y part: 16 b x 64 floats
        if (mode <= 1) {                   // x: read-only input, plain cached loads
            int bl2 = tid >> 4, j = tid & 15;
            int te = (mode == 0) ? (dir ? (SEQL - 1 - tval) : tval) : (SEQL - 1);
            float4 v = ((const float4*)(x + ((b0 + bl2) * SEQL + te) * IN))[j];
            *(float4*)&um[bl2 * 516 + 4 * j] = v;
        } else {                           // ys: cross-block data -> sc1 loads
            int e = dir ? (L - 1 - tval) : tval;
            for (int i = tid; i < 16 * 64; i += 256) {
                int bl2 = i >> 6, j = i & 63;
                um[bl2 * 516 + j] = agent_ld(g_ys + (e * BB + b0 + bl2) * IN + j);
            }
        }
        // stage h part: 16 b x 256 floats, sc1 loads (cross-block, cross-XCD)
        for (int i = tid; i < 16 * 256; i += 256) {
            int bl2 = i >> 8, j = i & 255;
            um[bl2 * 516 + IN + j] = agent_ld(hsrc + (dir * BB + b0 + bl2) * HH + j);
        }
        __syncthreads();

        float a0 = bias.x, a1 = bias.y, a2 = bias.z, a3 = bias.w;
        const float* arow = &um[bl * 516];
        #pragma unroll 4
        for (int k4 = 0; k4 < KTOT / 4; ++k4) {
            float4 av = *(const float4*)&arow[4 * k4];
            float4 w0 = w4[(4 * k4 + 0) * 16 + nl];
            float4 w1 = w4[(4 * k4 + 1) * 16 + nl];
            float4 w2 = w4[(4 * k4 + 2) * 16 + nl];
            float4 w3 = w4[(4 * k4 + 3) * 16 + nl];
            a0 = fmaf(av.x, w0.x, a0); a1 = fmaf(av.x, w0.y, a1); a2 = fmaf(av.x, w0.z, a2); a3 = fmaf(av.x, w0.w, a3);
            a0 = fmaf(av.y, w1.x, a0); a1 = fmaf(av.y, w1.y, a1); a2 = fmaf(av.y, w1.z, a2); a3 = fmaf(av.y, w1.w, a3);
            a0 = fmaf(av.z, w2.x, a0); a1 = fmaf(av.z, w2.y, a1); a2 = fmaf(av.z, w2.z, a2); a3 = fmaf(av.z, w2.w, a3);
            a0 = fmaf(av.w, w3.x, a0); a1 = fmaf(av.w, w3.y, a1); a2 = fmaf(av.w, w3.z, a2); a3 = fmaf(av.w, w3.w, a3);
        }
        float ig = sigm(a0);
        float fg = sigm(a1);
        float gt = tanhf(a2);
        float og = sigm(a3);
        c = fg * c + ig * gt;
        float hn = og * tanhf(c);
        agent_st(&g_h[p ^ 1][(dir * BB + b) * HH + n], hn);
        p ^= 1;
    };

    // ---------------- encoder: 336 steps ----------------
    load_w(g_wt_enc, g_bs_enc);
    for (int t = 0; t < SEQL; ++t) { step(0, t, 0); sync_g(16); }

    // switch to decoder weights (LDS reuse protected by the barrier in load_w/sync_g)
    load_w(g_wt_dec, g_bs_dec);

    // ---------------- decoder: 24 iterations ----------------
    for (int t = 0; t < PREDN; ++t) {
        int L = t ? t : 1;
        for (int s = 0; s < L; ++s) {
            step((t == 0) ? 1 : 2, s, L);
            sync_g((s == L - 1) ? 32 : 16);    // final sub-step: align both dirs for head
        }
        // ---- linear head: y = concat(hF,hB) @ linW^T + b; 16 b x 2 o per block ----
        {
            float* hc = g_h[p];
            for (int i = tid; i < 16 * 512; i += 256) {     // 16 b x 512 k via sc1 loads
                int bl2 = i >> 9, j = i & 511;
                const float* base = (j < 256) ? (hc + (b0 + bl2) * HH + j)
                                              : (hc + (BB + b0 + bl2) * HH + (j - 256));
                um[bl2 * 516 + j] = agent_ld(base);
            }
            __syncthreads();
            int bl2 = tid >> 4, ks = tid & 15;
            int o0  = ((dir << 4) | ntile) << 1;            // 2 outputs per block
            float p0 = 0.0f, p1 = 0.0f;
            const float* hr = &um[bl2 * 516 + ks * 32];
            const float* lw = g_linwt + (ks * 32) * IN + o0;
            #pragma unroll 8
            for (int j = 0; j < 32; ++j) {
                float hv = hr[j];
                p0 = fmaf(hv, lw[j * IN],     p0);
                p1 = fmaf(hv, lw[j * IN + 1], p1);
            }
            part[(bl2 * 16 + ks) * 2]     = p0;
            part[(bl2 * 16 + ks) * 2 + 1] = p1;
            __syncthreads();
            if (tid < 32) {
                int b2 = tid >> 1, oi = tid & 1;
                float acc = g_linb[o0 + oi];
                #pragma unroll
                for (int m2 = 0; m2 < 16; ++m2) acc += part[(b2 * 16 + m2) * 2 + oi];
                agent_st(&g_ys[(t * BB + b0 + b2) * IN + o0 + oi], acc);  // fp32 feedback
                out[(b0 + b2) * (PREDN * IN) + t * IN + o0 + oi] = acc;   // fp32 output
            }
            sync_g(32);
        }
    }
}

extern "C" void kernel_launch(void* const* d_in, const int* in_sizes, int n_in,
                              void* d_out, int out_size, void* d_ws, size_t ws_size,
                              hipStream_t stream)
{
    (void)in_sizes; (void)n_in; (void)out_size; (void)d_ws; (void)ws_size;
    const float* x    = (const float*)d_in[0];
    const float* eWih = (const float*)d_in[1];
    const float* eWhh = (const float*)d_in[2];
    const float* ebih = (const float*)d_in[3];
    const float* ebhh = (const float*)d_in[4];
    const float* dWih = (const float*)d_in[5];
    const float* dWhh = (const float*)d_in[6];
    const float* dbih = (const float*)d_in[7];
    const float* dbhh = (const float*)d_in[8];
    const float* linW = (const float*)d_in[9];
    const float* linb = (const float*)d_in[10];
    float* out = (float*)d_out;

    int prep_blocks = (N_PREP + 255) / 256;
    hipLaunchKernelGGL(prep_kernel, dim3(prep_blocks), dim3(256), 0, stream,
                       eWih, eWhh, ebih, ebhh, dWih, dWhh, dbih, dbhh, linW, linb);

    void* args[] = { (void*)&x, (void*)&out };
    (void)hipLaunchCooperativeKernel((void*)lstm_main, dim3(NBLK), dim3(256), args, 0, stream);
}

// Round 10
// 3851.991 us; speedup vs baseline: 8.3329x; 1.6674x over previous
//
#include <hip/hip_runtime.h>

#define BB    128
#define SEQL  336
#define PREDN 24
#define IN    64
#define HH    256
#define GG    1024          // 4*H
#define KTOT  320           // IN + H
#define NBLK  256

// ---- static device scratch (~7 MB .bss; re-initialized by prep every call) ----
__device__ float g_wt_enc[2 * KTOT * GG];    // [dir][k][n][gate] float4-interleaved
__device__ float g_wt_dec[2 * KTOT * GG];
__device__ float g_linwt[2 * HH * IN];       // [k2][o]
__device__ float g_bs_enc[2 * GG];
__device__ float g_bs_dec[2 * GG];
__device__ float g_linb[IN];
__device__ float g_h[2][2 * BB * HH];        // ping-pong [p][dir][b][n]
__device__ float g_ys[PREDN * BB * IN];      // fp32 decoder feedback
__device__ int   g_flag[NBLK * 16];          // per-block event counter, 64 B apart

#define N_WT   (2 * KTOT * GG)               // 655360
#define N_PREP (2 * N_WT + 2 * HH * IN + 4 * GG + IN + 2 * 2 * BB * HH + PREDN * BB * IN + NBLK * 16)

// Transpose weights into [dir][k][n][gate] (float4 per n), combine biases,
// zero h/ys/flags. ALL INPUTS ARE FLOAT32.
__global__ void prep_kernel(const float* __restrict__ eWih,
                            const float* __restrict__ eWhh,
                            const float* __restrict__ ebih,
                            const float* __restrict__ ebhh,
                            const float* __restrict__ dWih,
                            const float* __restrict__ dWhh,
                            const float* __restrict__ dbih,
                            const float* __restrict__ dbhh,
                            const float* __restrict__ linW,
                            const float* __restrict__ linb)
{
    int idx = blockIdx.x * 256 + threadIdx.x;
    if (idx >= N_PREP) return;

    if (idx < N_WT) {                 // enc
        int d  = idx / (KTOT * GG);
        int r2 = idx % (KTOT * GG);
        int k  = r2 / GG;
        int q  = r2 % GG;
        int nn = q >> 2, g = q & 3;
        int j  = g * HH + nn;
        g_wt_enc[idx] = (k < IN) ? eWih[(d * GG + j) * IN + k]
                                 : eWhh[(d * GG + j) * HH + (k - IN)];
        return;
    }
    idx -= N_WT;
    if (idx < N_WT) {                 // dec
        int d  = idx / (KTOT * GG);
        int r2 = idx % (KTOT * GG);
        int k  = r2 / GG;
        int q  = r2 % GG;
        int nn = q >> 2, g = q & 3;
        int j  = g * HH + nn;
        g_wt_dec[idx] = (k < IN) ? dWih[(d * GG + j) * IN + k]
                                 : dWhh[(d * GG + j) * HH + (k - IN)];
        return;
    }
    idx -= N_WT;
    if (idx < 2 * HH * IN) {          // linWT[k2][o]
        int k = idx / IN, o = idx % IN;
        g_linwt[idx] = linW[o * (2 * HH) + k];
        return;
    }
    idx -= 2 * HH * IN;
    if (idx < 2 * GG) { g_bs_enc[idx] = ebih[idx] + ebhh[idx]; return; }
    idx -= 2 * GG;
    if (idx < 2 * GG) { g_bs_dec[idx] = dbih[idx] + dbhh[idx]; return; }
    idx -= 2 * GG;
    if (idx < IN) { g_linb[idx] = linb[idx]; return; }
    idx -= IN;
    if (idx < 2 * 2 * BB * HH) { ((float*)g_h)[idx] = 0.0f; return; }
    idx -= 2 * 2 * BB * HH;
    if (idx < PREDN * BB * IN) { g_ys[idx] = 0.0f; return; }
    idx -= PREDN * BB * IN;
    if (idx < NBLK * 16) { g_flag[idx] = 0; return; }
}

__device__ __forceinline__ float sigm(float v) { return 1.0f / (1.0f + expf(-v)); }

__device__ __forceinline__ float agent_ld(const float* p) {
    return __hip_atomic_load(p, __ATOMIC_RELAXED, __HIP_MEMORY_SCOPE_AGENT);
}
__device__ __forceinline__ void agent_st(float* p, float v) {
    __hip_atomic_store(p, v, __ATOMIC_RELAXED, __HIP_MEMORY_SCOPE_AGENT);
}

// Persistent cooperative kernel. 256 blocks x 256 threads.
// blk = dir*128 + btile*16 + ntile. Thread: nl=tid&15 (n), bl=tid>>4 (b).
// Weights live in LDS for a whole phase. Recurrence closes within the
// 16-block (dir,btile) group. Cross-block data (g_h, g_ys) moves via 32-bit
// RELAXED agent-scope atomics (sc1 -> Infinity-Cache coherence point; no
// cache-maint fences). KEY (round 10): staging loads are hoisted into
// registers BEFORE any LDS write -- monotonic atomics are not reordered by
// the scheduler, so load->ds_write per element serialized into 16 IC
// round-trips/step (~6 us) in round 9. Load-all-then-write-all pipelines
// them into ~1 round-trip.
__global__ __launch_bounds__(256)
void lstm_main(const float* __restrict__ x, float* __restrict__ out)
{
    __shared__ float4 w4[KTOT * 16];                     // 81920 B [k][n_local]
    __shared__ __align__(16) float um[16 * 516];         // 33024 B acts rows (stride 516)
    __shared__ float part[16 * 16 * 2];                  //  2048 B head partials

    const int tid   = threadIdx.x;
    const int blk   = blockIdx.x;
    const int dir   = blk >> 7;
    const int btile = (blk >> 4) & 7;
    const int ntile = blk & 15;
    const int nl    = tid & 15;
    const int bl    = tid >> 4;
    const int n0    = ntile * 16;
    const int b0    = btile * 16;
    const int n     = n0 + nl;
    const int b     = b0 + bl;

    int* myflag = &g_flag[blk * 16];
    int  ev = 0;

    // group sync: drain own sc1 stores (per wave!), raise own flag (relaxed),
    // poll group members' flags (relaxed). Zero cache-maintenance ops.
    auto sync_g = [&](int nwait) {
        ++ev;
        __atomic_signal_fence(__ATOMIC_SEQ_CST);
        __builtin_amdgcn_s_waitcnt(0);     // this wave's h/ys stores reached IC
        __atomic_signal_fence(__ATOMIC_SEQ_CST);
        __syncthreads();                   // all waves drained
        if (tid == 0)
            __hip_atomic_store(myflag, ev, __ATOMIC_RELAXED, __HIP_MEMORY_SCOPE_AGENT);
        if (tid < nwait) {
            int d = (nwait == 32) ? (tid >> 4) : dir;
            int m = tid & 15;
            int* f = &g_flag[(((d << 3) | btile) * 16 + m) * 16];
            while (__hip_atomic_load(f, __ATOMIC_RELAXED, __HIP_MEMORY_SCOPE_AGENT) < ev)
                __builtin_amdgcn_s_sleep(1);
        }
        __atomic_signal_fence(__ATOMIC_SEQ_CST);
        __syncthreads();
    };

    float4 bias;
    auto load_w = [&](const float* wsrc, const float* bsrc) {
        const float4* w4g = (const float4*)wsrc + dir * (KTOT * 256);
        for (int i = tid; i < KTOT * 16; i += 256) {
            int k = i >> 4, nn = i & 15;
            w4[i] = w4g[k * 256 + n0 + nn];
        }
        const float* bs = bsrc + dir * GG;
        bias = make_float4(bs[n], bs[256 + n], bs[512 + n], bs[768 + n]);
        __syncthreads();
    };

    float c = 0.0f;
    int   p = 0;

    // mode 0: encoder step tval (dir-reflected); 1: decoder t=0 (x last step);
    // 2: decoder feedback sub-step tval of length L (dir-reflected).
    auto step = [&](int mode, int tval, int L) {
        float* hsrc = g_h[p];
        // ---- phase 1: issue ALL staging loads into registers (pipelined) ----
        float4 xv;                           // x/ys part: 64 floats/row, 16 rows
        float  yv[4];
        if (mode <= 1) {                     // x: read-only input, plain cached load
            int bl2 = tid >> 4, j = tid & 15;
            int te = (mode == 0) ? (dir ? (SEQL - 1 - tval) : tval) : (SEQL - 1);
            xv = ((const float4*)(x + ((b0 + bl2) * SEQL + te) * IN))[j];
        } else {                             // ys: cross-block -> sc1 atomic loads
            int e = dir ? (L - 1 - tval) : tval;
            #pragma unroll
            for (int jj = 0; jj < 4; ++jj) {
                int i = tid + jj * 256;      // 16 rows x 64 cols
                int bl2 = i >> 6, j = i & 63;
                yv[jj] = agent_ld(g_ys + (e * BB + b0 + bl2) * IN + j);
            }
        }
        float rh[16];                        // h part: 16 rows x 256 cols
        #pragma unroll
        for (int jj = 0; jj < 16; ++jj)      // row jj, col tid -> coalesced
            rh[jj] = agent_ld(hsrc + (dir * BB + b0 + jj) * HH + tid);

        // ---- phase 2: write registers to LDS ----
        if (mode <= 1) {
            int bl2 = tid >> 4, j = tid & 15;
            *(float4*)&um[bl2 * 516 + 4 * j] = xv;
        } else {
            #pragma unroll
            for (int jj = 0; jj < 4; ++jj) {
                int i = tid + jj * 256;
                int bl2 = i >> 6, j = i & 63;
                um[bl2 * 516 + j] = yv[jj];
            }
        }
        #pragma unroll
        for (int jj = 0; jj < 16; ++jj)
            um[jj * 516 + IN + tid] = rh[jj];
        __syncthreads();

        float a0 = bias.x, a1 = bias.y, a2 = bias.z, a3 = bias.w;
        const float* arow = &um[bl * 516];
        #pragma unroll 4
        for (int k4 = 0; k4 < KTOT / 4; ++k4) {
            float4 av = *(const float4*)&arow[4 * k4];
            float4 w0 = w4[(4 * k4 + 0) * 16 + nl];
            float4 w1 = w4[(4 * k4 + 1) * 16 + nl];
            float4 w2 = w4[(4 * k4 + 2) * 16 + nl];
            float4 w3 = w4[(4 * k4 + 3) * 16 + nl];
            a0 = fmaf(av.x, w0.x, a0); a1 = fmaf(av.x, w0.y, a1); a2 = fmaf(av.x, w0.z, a2); a3 = fmaf(av.x, w0.w, a3);
            a0 = fmaf(av.y, w1.x, a0); a1 = fmaf(av.y, w1.y, a1); a2 = fmaf(av.y, w1.z, a2); a3 = fmaf(av.y, w1.w, a3);
            a0 = fmaf(av.z, w2.x, a0); a1 = fmaf(av.z, w2.y, a1); a2 = fmaf(av.z, w2.z, a2); a3 = fmaf(av.z, w2.w, a3);
            a0 = fmaf(av.w, w3.x, a0); a1 = fmaf(av.w, w3.y, a1); a2 = fmaf(av.w, w3.z, a2); a3 = fmaf(av.w, w3.w, a3);
        }
        float ig = sigm(a0);
        float fg = sigm(a1);
        float gt = tanhf(a2);
        float og = sigm(a3);
        c = fg * c + ig * gt;
        float hn = og * tanhf(c);
        agent_st(&g_h[p ^ 1][(dir * BB + b) * HH + n], hn);
        p ^= 1;
    };

    // ---------------- encoder: 336 steps ----------------
    load_w(g_wt_enc, g_bs_enc);
    for (int t = 0; t < SEQL; ++t) { step(0, t, 0); sync_g(16); }

    // switch to decoder weights (LDS reuse protected by the barrier in load_w/sync_g)
    load_w(g_wt_dec, g_bs_dec);

    // ---------------- decoder: 24 iterations ----------------
    for (int t = 0; t < PREDN; ++t) {
        int L = t ? t : 1;
        for (int s = 0; s < L; ++s) {
            step((t == 0) ? 1 : 2, s, L);
            sync_g((s == L - 1) ? 32 : 16);    // final sub-step: align both dirs for head
        }
        // ---- linear head: y = concat(hF,hB) @ linW^T + b; 16 b x 2 o per block ----
        {
            float* hc = g_h[p];
            float rh2[32];                     // 16 b x 512 k, loads-then-writes
            #pragma unroll
            for (int jj = 0; jj < 32; ++jj) {
                int i = tid + jj * 256;
                int bl2 = i >> 9, j = i & 511;
                const float* base = (j < 256) ? (hc + (b0 + bl2) * HH + j)
                                              : (hc + (BB + b0 + bl2) * HH + (j - 256));
                rh2[jj] = agent_ld(base);
            }
            #pragma unroll
            for (int jj = 0; jj < 32; ++jj) {
                int i = tid + jj * 256;
                int bl2 = i >> 9, j = i & 511;
                um[bl2 * 516 + j] = rh2[jj];
            }
            __syncthreads();
            int bl2 = tid >> 4, ks = tid & 15;
            int o0  = ((dir << 4) | ntile) << 1;            // 2 outputs per block
            float p0 = 0.0f, p1 = 0.0f;
            const float* hr = &um[bl2 * 516 + ks * 32];
            const float* lw = g_linwt + (ks * 32) * IN + o0;
            #pragma unroll 8
            for (int j = 0; j < 32; ++j) {
                float hv = hr[j];
                p0 = fmaf(hv, lw[j * IN],     p0);
                p1 = fmaf(hv, lw[j * IN + 1], p1);
            }
            part[(bl2 * 16 + ks) * 2]     = p0;
            part[(bl2 * 16 + ks) * 2 + 1] = p1;
            __syncthreads();
            if (tid < 32) {
                int b2 = tid >> 1, oi = tid & 1;
                float acc = g_linb[o0 + oi];
                #pragma unroll
                for (int m2 = 0; m2 < 16; ++m2) acc += part[(b2 * 16 + m2) * 2 + oi];
                agent_st(&g_ys[(t * BB + b0 + b2) * IN + o0 + oi], acc);  // fp32 feedback
                out[(b0 + b2) * (PREDN * IN) + t * IN + o0 + oi] = acc;   // fp32 output
            }
            sync_g(32);
        }
    }
}

extern "C" void kernel_launch(void* const* d_in, const int* in_sizes, int n_in,
                              void* d_out, int out_size, void* d_ws, size_t ws_size,
                              hipStream_t stream)
{
    (void)in_sizes; (void)n_in; (void)out_size; (void)d_ws; (void)ws_size;
    const float* x    = (const float*)d_in[0];
    const float* eWih = (const float*)d_in[1];
    const float* eWhh = (const float*)d_in[2];
    const float* ebih = (const float*)d_in[3];
    const float* ebhh = (const float*)d_in[4];
    const float* dWih = (const float*)d_in[5];
    const float* dWhh = (const float*)d_in[6];
    const float* dbih = (const float*)d_in[7];
    const float* dbhh = (const float*)d_in[8];
    const float* linW = (const float*)d_in[9];
    const float* linb = (const float*)d_in[10];
    float* out = (float*)d_out;

    int prep_blocks = (N_PREP + 255) / 256;
    hipLaunchKernelGGL(prep_kernel, dim3(prep_blocks), dim3(256), 0, stream,
                       eWih, eWhh, ebih, ebhh, dWih, dWhh, dbih, dbhh, linW, linb);

    void* args[] = { (void*)&x, (void*)&out };
    (void)hipLaunchCooperativeKernel((void*)lstm_main, dim3(NBLK), dim3(256), args, 0, stream);
}

// Round 11
// 3409.561 us; speedup vs baseline: 9.4142x; 1.1298x over previous
//
#include <hip/hip_runtime.h>

#define BB    128
#define SEQL  336
#define PREDN 24
#define IN    64
#define HH    256
#define GG    1024          // 4*H
#define KTOT  320           // IN + H
#define NBLK  256

typedef unsigned int  uint_t;
typedef unsigned short ush;
using s8v = __attribute__((ext_vector_type(8))) short;   // 8 bf16 (4 VGPRs)
using f4v = __attribute__((ext_vector_type(4))) float;   // MFMA acc

// ---- static device scratch (.bss; re-initialized by prep every call) ----
__device__ ush   g_webh[2 * 4 * 256 * KTOT];  // enc W bf16-hi  [dir][g][n][k]
__device__ ush   g_webl[2 * 4 * 256 * KTOT];  // enc W bf16-lo
__device__ ush   g_wdbh[2 * 4 * 256 * KTOT];  // dec W bf16-hi
__device__ ush   g_wdbl[2 * 4 * 256 * KTOT];  // dec W bf16-lo
__device__ float g_linwt[2 * HH * IN];        // [k2][o]
__device__ float g_bs_enc[2 * GG];
__device__ float g_bs_dec[2 * GG];
__device__ float g_linb[IN];
__device__ float g_h[2][2 * BB * HH];         // ping-pong [p][dir][b][n]
__device__ float g_ys[PREDN * BB * IN];       // fp32 decoder feedback
__device__ int   g_flag[NBLK * 16];           // per-block event counter, 64 B apart

#define N_WT   (2 * 4 * 256 * KTOT)           // 655360 (elements; hi+lo written together)
#define N_PREP (2 * N_WT + 2 * HH * IN + 4 * GG + IN + 2 * 2 * BB * HH + PREDN * BB * IN + NBLK * 16)

__device__ __forceinline__ void bfsplit(float v, uint_t& hi, uint_t& lo) {
    uint_t u = __float_as_uint(v);
    uint_t h = (u + 0x7FFFu + ((u >> 16) & 1u)) >> 16;          // RTN-even bf16
    float  r = v - __uint_as_float(h << 16);
    uint_t u2 = __float_as_uint(r);
    uint_t l = (u2 + 0x7FFFu + ((u2 >> 16) & 1u)) >> 16;
    hi = h; lo = l;
}

// Weights -> bf16 hi/lo [dir][gate][n][k]; combine biases; zero h/ys/flags.
__global__ void prep_kernel(const float* __restrict__ eWih,
                            const float* __restrict__ eWhh,
                            const float* __restrict__ ebih,
                            const float* __restrict__ ebhh,
                            const float* __restrict__ dWih,
                            const float* __restrict__ dWhh,
                            const float* __restrict__ dbih,
                            const float* __restrict__ dbhh,
                            const float* __restrict__ linW,
                            const float* __restrict__ linb)
{
    int idx = blockIdx.x * 256 + threadIdx.x;
    if (idx >= N_PREP) return;

    if (idx < N_WT) {                 // enc
        int d   = idx / (4 * 256 * KTOT);
        int sub = idx % (4 * 256 * KTOT);
        int g   = sub / (256 * KTOT);
        int n2  = (sub / KTOT) % 256;
        int k   = sub % KTOT;
        int j   = g * HH + n2;
        float v = (k < IN) ? eWih[(d * GG + j) * IN + k]
                           : eWhh[(d * GG + j) * HH + (k - IN)];
        uint_t hi, lo; bfsplit(v, hi, lo);
        g_webh[idx] = (ush)hi; g_webl[idx] = (ush)lo;
        return;
    }
    idx -= N_WT;
    if (idx < N_WT) {                 // dec
        int d   = idx / (4 * 256 * KTOT);
        int sub = idx % (4 * 256 * KTOT);
        int g   = sub / (256 * KTOT);
        int n2  = (sub / KTOT) % 256;
        int k   = sub % KTOT;
        int j   = g * HH + n2;
        float v = (k < IN) ? dWih[(d * GG + j) * IN + k]
                           : dWhh[(d * GG + j) * HH + (k - IN)];
        uint_t hi, lo; bfsplit(v, hi, lo);
        g_wdbh[idx] = (ush)hi; g_wdbl[idx] = (ush)lo;
        return;
    }
    idx -= N_WT;
    if (idx < 2 * HH * IN) {          // linWT[k2][o]
        int k = idx / IN, o = idx % IN;
        g_linwt[idx] = linW[o * (2 * HH) + k];
        return;
    }
    idx -= 2 * HH * IN;
    if (idx < 2 * GG) { g_bs_enc[idx] = ebih[idx] + ebhh[idx]; return; }
    idx -= 2 * GG;
    if (idx < 2 * GG) { g_bs_dec[idx] = dbih[idx] + dbhh[idx]; return; }
    idx -= 2 * GG;
    if (idx < IN) { g_linb[idx] = linb[idx]; return; }
    idx -= IN;
    if (idx < 2 * 2 * BB * HH) { ((float*)g_h)[idx] = 0.0f; return; }
    idx -= 2 * 2 * BB * HH;
    if (idx < PREDN * BB * IN) { g_ys[idx] = 0.0f; return; }
    idx -= PREDN * BB * IN;
    if (idx < NBLK * 16) { g_flag[idx] = 0; return; }
}

__device__ __forceinline__ float sigm(float v) { return 1.0f / (1.0f + expf(-v)); }

__device__ __forceinline__ float agent_ld(const float* p) {
    return __hip_atomic_load(p, __ATOMIC_RELAXED, __HIP_MEMORY_SCOPE_AGENT);
}
__device__ __forceinline__ void agent_st(float* p, float v) {
    __hip_atomic_store(p, v, __ATOMIC_RELAXED, __HIP_MEMORY_SCOPE_AGENT);
}

// Persistent cooperative kernel. 256 blocks x 256 threads.
// blk = dir*128 + btile*16 + ntile. Per step, block computes the GEMM
// D[16b x 16n x 4g] = A[16b x 320k] . W via mfma_f32_16x16x32_bf16 with
// fp32 hi/lo splitting (3 MFMAs per K-chunk, rel err ~2^-17). Wave w = gate w.
// A/B frags stored PRE-SWIZZLED in LDS frag order -> every ds_read_b128 is a
// dense 1KB wave read (round 10's 1.6 MB/step LDS weight delivery -> 160 KB).
// Cross-block h/ys via relaxed agent (sc1/IC) atomics; flag sync as before.
// Frag layouts (HW-verified, learn_hip m89/m118/m120):
//   A[m=lane&15][k=quad*8+j]  B[n=lane&15][k=quad*8+j]  D[row=quad*4+reg][col=lane&15]
__global__ __launch_bounds__(256)
void lstm_main(const float* __restrict__ x, float* __restrict__ out)
{
    __shared__ __align__(16) ush  sAh[10 * 64 * 8];       // 10 KB  A hi (frag order)
    __shared__ __align__(16) ush  sAl[10 * 64 * 8];       // 10 KB  A lo
    __shared__ __align__(16) ush  sBh[4 * 10 * 64 * 8];   // 40 KB  W hi, 4 gates
    __shared__ __align__(16) ush  sBl[4 * 10 * 64 * 8];   // 40 KB  W lo
    __shared__ float gbuf[4 * 16 * 16];                   //  4 KB  gate exchange
    __shared__ float um[16 * 516];                        // 33 KB  head h staging
    __shared__ float part[16 * 16 * 2];                   //  2 KB  head partials

    const int tid   = threadIdx.x;
    const int blk   = blockIdx.x;
    const int dir   = blk >> 7;
    const int btile = (blk >> 4) & 7;
    const int ntile = blk & 15;
    const int nl    = tid & 15;
    const int bl    = tid >> 4;
    const int n0    = ntile * 16;
    const int b0    = btile * 16;
    const int n     = n0 + nl;
    const int b     = b0 + bl;
    const int lane  = tid & 63;
    const int wave  = tid >> 6;       // = gate index

    int* myflag = &g_flag[blk * 16];
    int  ev = 0;

    auto sync_g = [&](int nwait) {
        ++ev;
        __atomic_signal_fence(__ATOMIC_SEQ_CST);
        __builtin_amdgcn_s_waitcnt(0);     // this wave's sc1 stores reached IC
        __atomic_signal_fence(__ATOMIC_SEQ_CST);
        __syncthreads();
        if (tid == 0)
            __hip_atomic_store(myflag, ev, __ATOMIC_RELAXED, __HIP_MEMORY_SCOPE_AGENT);
        if (tid < nwait) {
            int d = (nwait == 32) ? (tid >> 4) : dir;
            int m = tid & 15;
            int* f = &g_flag[(((d << 3) | btile) * 16 + m) * 16];
            while (__hip_atomic_load(f, __ATOMIC_RELAXED, __HIP_MEMORY_SCOPE_AGENT) < ev)
                __builtin_amdgcn_s_sleep(1);
        }
        __atomic_signal_fence(__ATOMIC_SEQ_CST);
        __syncthreads();
    };

    float bw;                              // this wave's gate bias at its n-col
    auto load_w = [&](const ush* wh, const ush* wl, const float* bsrc) {
        wh += dir * (4 * 256 * KTOT);
        wl += dir * (4 * 256 * KTOT);
        for (int i = tid; i < 4 * 16 * 80; i += 256) {   // k-runs of 4
            int g   = i / (16 * 80);
            int r   = i % (16 * 80);
            int nl_ = r / 80;
            int k   = (r % 80) * 4;
            int src = ((g * 256) + n0 + nl_) * KTOT + k;
            int kc = k >> 5, quad = (k & 31) >> 3, j = k & 7;
            int dst = ((g * 10 + kc) * 64 + quad * 16 + nl_) * 8 + j;
            *(uint2*)&sBh[dst] = *(const uint2*)(wh + src);
            *(uint2*)&sBl[dst] = *(const uint2*)(wl + src);
        }
        bw = bsrc[dir * GG + wave * HH + n0 + (lane & 15)];
        __syncthreads();
    };

    float c = 0.0f;
    int   p = 0;

    // mode 0: encoder step tval; 1: decoder t=0 (x last step); 2: ys sub-step.
    auto step = [&](int mode, int tval, int L) {
        float* hsrc = g_h[p];
        // ---- stage x/ys into A frags (cols 0..63) ----
        if (mode <= 1) {
            int xb = tid >> 4, xj = tid & 15;            // b-row, col quad 4*xj
            int te = (mode == 0) ? (dir ? (SEQL - 1 - tval) : tval) : (SEQL - 1);
            float4 xv = ((const float4*)(x + ((b0 + xb) * SEQL + te) * IN))[xj];
            uint_t h0,l0,h1,l1,h2,l2,h3,l3;
            bfsplit(xv.x,h0,l0); bfsplit(xv.y,h1,l1); bfsplit(xv.z,h2,l2); bfsplit(xv.w,h3,l3);
            int k = 4 * xj;
            int base = (((k >> 5) * 64 + ((k & 31) >> 3) * 16 + xb) * 8) + (k & 7);
            *(uint_t*)&sAh[base]     = h0 | (h1 << 16);
            *(uint_t*)&sAh[base + 2] = h2 | (h3 << 16);
            *(uint_t*)&sAl[base]     = l0 | (l1 << 16);
            *(uint_t*)&sAl[base + 2] = l2 | (l3 << 16);
        } else {
            int e = dir ? (L - 1 - tval) : tval;
            float yv[4];
            #pragma unroll
            for (int jj = 0; jj < 4; ++jj) {
                int i = tid + jj * 256;
                yv[jj] = agent_ld(g_ys + (e * BB + b0 + (i >> 6)) * IN + (i & 63));
            }
            #pragma unroll
            for (int jj = 0; jj < 4; ++jj) {
                int i = tid + jj * 256;
                int yb = i >> 6, k = i & 63;
                uint_t hi, lo; bfsplit(yv[jj], hi, lo);
                int base = (((k >> 5) * 64 + ((k & 31) >> 3) * 16 + yb) * 8) + (k & 7);
                sAh[base] = (ush)hi; sAl[base] = (ush)lo;
            }
        }
        // ---- stage h into A frags (cols 64..319): row-wise, pipelined sc1 loads ----
        {
            int hb = tid & 15, cblk = tid >> 4;
            const float* hp = hsrc + (dir * BB + b0 + hb) * HH + cblk * 16;
            float rh[16];
            #pragma unroll
            for (int m = 0; m < 16; ++m) rh[m] = agent_ld(hp + m);
            #pragma unroll
            for (int m = 0; m < 16; m += 2) {
                int k = IN + cblk * 16 + m;
                uint_t h0,l0,h1,l1;
                bfsplit(rh[m], h0, l0); bfsplit(rh[m+1], h1, l1);
                int base = (((k >> 5) * 64 + ((k & 31) >> 3) * 16 + hb) * 8) + (k & 7);
                *(uint_t*)&sAh[base] = h0 | (h1 << 16);
                *(uint_t*)&sAl[base] = l0 | (l1 << 16);
            }
        }
        __syncthreads();

        // ---- MFMA K-loop: wave computes its gate's [16b x 16n] preactivation ----
        f4v acc = { bw, bw, bw, bw };
        const s8v* pAh = (const s8v*)sAh;
        const s8v* pAl = (const s8v*)sAl;
        const s8v* pBh = (const s8v*)sBh + wave * 10 * 64;
        const s8v* pBl = (const s8v*)sBl + wave * 10 * 64;
        #pragma unroll
        for (int kc = 0; kc < 10; ++kc) {
            s8v ah = pAh[kc * 64 + lane];
            s8v al = pAl[kc * 64 + lane];
            s8v bh = pBh[kc * 64 + lane];
            s8v blo = pBl[kc * 64 + lane];
            acc = __builtin_amdgcn_mfma_f32_16x16x32_bf16(ah, bh,  acc, 0, 0, 0);
            acc = __builtin_amdgcn_mfma_f32_16x16x32_bf16(ah, blo, acc, 0, 0, 0);
            acc = __builtin_amdgcn_mfma_f32_16x16x32_bf16(al, bh,  acc, 0, 0, 0);
        }
        // ---- exchange gates via LDS; thread (bl,nl) finalizes its cell ----
        {
            int quad = lane >> 4, ncol = lane & 15;
            #pragma unroll
            for (int r2 = 0; r2 < 4; ++r2)
                gbuf[(wave * 16 + quad * 4 + r2) * 16 + ncol] = acc[r2];
        }
        __syncthreads();
        {
            float gi_ = gbuf[(0 * 16 + bl) * 16 + nl];
            float gf_ = gbuf[(1 * 16 + bl) * 16 + nl];
            float gg_ = gbuf[(2 * 16 + bl) * 16 + nl];
            float go_ = gbuf[(3 * 16 + bl) * 16 + nl];
            c = sigm(gf_) * c + sigm(gi_) * tanhf(gg_);
            float hn = sigm(go_) * tanhf(c);
            agent_st(&g_h[p ^ 1][(dir * BB + b) * HH + n], hn);
        }
        p ^= 1;
    };

    // ---------------- encoder: 336 steps ----------------
    load_w(g_webh, g_webl, g_bs_enc);
    for (int t = 0; t < SEQL; ++t) { step(0, t, 0); sync_g(16); }

    load_w(g_wdbh, g_wdbl, g_bs_dec);

    // ---------------- decoder: 24 iterations ----------------
    for (int t = 0; t < PREDN; ++t) {
        int L = t ? t : 1;
        for (int s = 0; s < L; ++s) {
            step((t == 0) ? 1 : 2, s, L);
            sync_g((s == L - 1) ? 32 : 16);
        }
        // ---- linear head: y = concat(hF,hB) @ linW^T + b; 16 b x 2 o per block ----
        {
            float* hc = g_h[p];
            float rh2[32];
            #pragma unroll
            for (int jj = 0; jj < 32; ++jj) {
                int i = tid + jj * 256;
                int bl2 = i >> 9, j = i & 511;
                const float* base = (j < 256) ? (hc + (b0 + bl2) * HH + j)
                                              : (hc + (BB + b0 + bl2) * HH + (j - 256));
                rh2[jj] = agent_ld(base);
            }
            #pragma unroll
            for (int jj = 0; jj < 32; ++jj) {
                int i = tid + jj * 256;
                int bl2 = i >> 9, j = i & 511;
                um[bl2 * 516 + j] = rh2[jj];
            }
            __syncthreads();
            int bl2 = tid >> 4, ks = tid & 15;
            int o0  = ((dir << 4) | ntile) << 1;
            float p0 = 0.0f, p1 = 0.0f;
            const float* hr = &um[bl2 * 516 + ks * 32];
            const float* lw = g_linwt + (ks * 32) * IN + o0;
            #pragma unroll 8
            for (int j = 0; j < 32; ++j) {
                float hv = hr[j];
                p0 = fmaf(hv, lw[j * IN],     p0);
                p1 = fmaf(hv, lw[j * IN + 1], p1);
            }
            part[(bl2 * 16 + ks) * 2]     = p0;
            part[(bl2 * 16 + ks) * 2 + 1] = p1;
            __syncthreads();
            if (tid < 32) {
                int b2 = tid >> 1, oi = tid & 1;
                float acc2 = g_linb[o0 + oi];
                #pragma unroll
                for (int m2 = 0; m2 < 16; ++m2) acc2 += part[(b2 * 16 + m2) * 2 + oi];
                agent_st(&g_ys[(t * BB + b0 + b2) * IN + o0 + oi], acc2);
                out[(b0 + b2) * (PREDN * IN) + t * IN + o0 + oi] = acc2;
            }
            sync_g(32);
        }
    }
}

extern "C" void kernel_launch(void* const* d_in, const int* in_sizes, int n_in,
                              void* d_out, int out_size, void* d_ws, size_t ws_size,
                              hipStream_t stream)
{
    (void)in_sizes; (void)n_in; (void)out_size; (void)d_ws; (void)ws_size;
    const float* x    = (const float*)d_in[0];
    const float* eWih = (const float*)d_in[1];
    const float* eWhh = (const float*)d_in[2];
    const float* ebih = (const float*)d_in[3];
    const float* ebhh = (const float*)d_in[4];
    const float* dWih = (const float*)d_in[5];
    const float* dWhh = (const float*)d_in[6];
    const float* dbih = (const float*)d_in[7];
    const float* dbhh = (const float*)d_in[8];
    const float* linW = (const float*)d_in[9];
    const float* linb = (const float*)d_in[10];
    float* out = (float*)d_out;

    int prep_blocks = (N_PREP + 255) / 256;
    hipLaunchKernelGGL(prep_kernel, dim3(prep_blocks), dim3(256), 0, stream,
                       eWih, eWhh, ebih, ebhh, dWih, dWhh, dbih, dbhh, linW, linb);

    void* args[] = { (void*)&x, (void*)&out };
    (void)hipLaunchCooperativeKernel((void*)lstm_main, dim3(NBLK), dim3(256), args, 0, stream);
}